// Round 4
// baseline (234.863 us; speedup 1.0000x reference)
//
#include <hip/hip_runtime.h>
#include <stdint.h>

#define DEV static __device__ __forceinline__

typedef __attribute__((ext_vector_type(8))) __bf16 bfx8;
typedef __attribute__((ext_vector_type(4))) float f32x4;

DEV short f2bfbits(float f) {
  union { float f; unsigned u; } v; v.f = f;
  unsigned r = v.u + 0x7fffu + ((v.u >> 16) & 1u);
  return (short)(r >> 16);
}

DEV void gload_lds16(const void* g, void* lds) {
  __builtin_amdgcn_global_load_lds(
      (const __attribute__((address_space(1))) void*)g,
      (__attribute__((address_space(3))) void*)lds, 16, 0, 0);
}

// ---------------- prep kernels ----------------

__global__ void k_cvt_x(const float* __restrict__ src, short* __restrict__ dst) {
  int i = blockIdx.x * 256 + threadIdx.x;            // 4 floats per thread
  float4 v = ((const float4*)src)[i];
  union { short s[4]; uint64_t u; } o;
  o.s[0] = f2bfbits(v.x); o.s[1] = f2bfbits(v.y);
  o.s[2] = f2bfbits(v.z); o.s[3] = f2bfbits(v.w);
  ((uint64_t*)dst)[i] = o.u;
}

// src [R][C] f32 -> dst [C][R] bf16
__global__ void k_transpose(const float* __restrict__ src, short* __restrict__ dst,
                            int R, int C) {
  __shared__ float tile[32][33];
  int c0 = blockIdx.x * 32, r0 = blockIdx.y * 32;
  int tx = threadIdx.x, ty = threadIdx.y;            // block (32,8)
  #pragma unroll
  for (int j = 0; j < 32; j += 8)
    tile[ty + j][tx] = src[(size_t)(r0 + ty + j) * C + c0 + tx];
  __syncthreads();
  #pragma unroll
  for (int j = 0; j < 32; j += 8)
    dst[(size_t)(c0 + ty + j) * R + r0 + tx] = f2bfbits(tile[tx][ty + j]);
}

// msk[b][n]: n==0 -> 1 else mask[b][n-1]
__global__ void k_mask(const int* __restrict__ mask, unsigned char* __restrict__ msk) {
  int i = blockIdx.x * 256 + threadIdx.x;            // [0, 4096)
  int b = i >> 10, n = i & 1023;
  msk[i] = (n == 0) ? (unsigned char)1 : (unsigned char)(mask[b * 1023 + n - 1] != 0);
}

// ---------------- GEMM: C = A[M][K] @ Bt[N][K]^T + bias ----------------
__global__ __launch_bounds__(256)
void k_gemm(const short* __restrict__ A, const short* __restrict__ Bt,
            const float* __restrict__ bias, int K, int mode,
            short* __restrict__ q, short* __restrict__ kk,
            short* __restrict__ vT, float* __restrict__ outF) {
  __shared__ short As[128 * 32];
  __shared__ short Bs[128 * 32];
  const int t = threadIdx.x;
  const int l = t & 63, w = t >> 6;
  const int lr = l & 15, lk = l >> 4;
  const int m0 = blockIdx.y * 128, n0 = blockIdx.x * 128;
  const int wr = (w >> 1) * 64, wc = (w & 1) * 64;
  f32x4 acc[4][4] = {};

  const int srow = t >> 2;
  const int sc8 = (t & 3) * 8;
  const size_t aoff1 = (size_t)(m0 + srow) * K + sc8;
  const size_t aoff2 = (size_t)(m0 + srow + 64) * K + sc8;
  const size_t boff1 = (size_t)(n0 + srow) * K + sc8;
  const size_t boff2 = (size_t)(n0 + srow + 64) * K + sc8;
  short* asd1 = As + (t & ~63) * 8;
  short* asd2 = As + (t & ~63) * 8 + 2048;
  short* bsd1 = Bs + (t & ~63) * 8;
  short* bsd2 = Bs + (t & ~63) * 8 + 2048;

  for (int k0 = 0; k0 < K; k0 += 32) {
    gload_lds16(A + aoff1 + k0, asd1);
    gload_lds16(A + aoff2 + k0, asd2);
    gload_lds16(Bt + boff1 + k0, bsd1);
    gload_lds16(Bt + boff2 + k0, bsd2);
    __syncthreads();
    bfx8 af[4], bf[4];
    #pragma unroll
    for (int m = 0; m < 4; m++)
      af[m] = *(const bfx8*)&As[(wr + m * 16 + lr) * 32 + lk * 8];
    #pragma unroll
    for (int n = 0; n < 4; n++)
      bf[n] = *(const bfx8*)&Bs[(wc + n * 16 + lr) * 32 + lk * 8];
    #pragma unroll
    for (int m = 0; m < 4; m++)
      #pragma unroll
      for (int n = 0; n < 4; n++)
        acc[m][n] = __builtin_amdgcn_mfma_f32_16x16x32_bf16(af[m], bf[n], acc[m][n], 0, 0, 0);
    __syncthreads();
  }

  if (mode == 0) {
    #pragma unroll
    for (int m = 0; m < 4; m++) {
      int grb = m0 + wr + m * 16 + 4 * lk;
      #pragma unroll
      for (int n = 0; n < 4; n++) {
        int gc = n0 + wc + n * 16 + lr;
        float bv = bias[gc];
        int which = gc >> 10, rem = gc & 1023;
        int hh = rem >> 6, dd = rem & 63;
        #pragma unroll
        for (int i = 0; i < 4; i++) {
          int gr = grb + i;
          int bb = gr >> 10, nn = gr & 1023;
          size_t bh = (size_t)(bb * 16 + hh);
          short val = f2bfbits(acc[m][n][i] + bv);
          if (which == 0)      q [(bh << 16) + ((size_t)nn << 6) + dd] = val;
          else if (which == 1) kk[(bh << 16) + ((size_t)nn << 6) + dd] = val;
          else                 vT[(bh << 16) + ((size_t)dd << 10) + nn] = val;
        }
      }
    }
  } else {
    #pragma unroll
    for (int m = 0; m < 4; m++) {
      #pragma unroll
      for (int n = 0; n < 4; n++) {
        int gc = n0 + wc + n * 16 + lr;
        float bv = bias[gc];
        #pragma unroll
        for (int i = 0; i < 4; i++) {
          int gr = m0 + wr + m * 16 + 4 * lk + i;
          outF[(size_t)gr * 1024 + gc] = acc[m][n][i] + bv;
        }
      }
    }
  }
}

// ---------------- fused attention v4 ----------------
// WG = (b,h) x 16 q-rows, 8 waves (512 thr). 2-phase double-buffered staging
// (stage next chunk, compute current, ONE __syncthreads per chunk). 8 waves
// split 1024 k-cols 8-ways in QK^T; (4 dim-grp x 2 col-half) in PV with 4KB
// cross-wave reduce. P bf16 in LDS (swizzled); attn streamed as 1KB lines.
__global__ __launch_bounds__(512, 4)
void k_attn(const short* __restrict__ q, const short* __restrict__ kmat,
            const short* __restrict__ vT, const unsigned char* __restrict__ msk,
            float* __restrict__ attn, short* __restrict__ ctx) {
  __shared__ short tile[2][8192];     // 2 x 16KB staging
  __shared__ short P[16 * 1024];      // 32KB bf16 P, swizzled 16B slots
  __shared__ float redM[16][8];
  __shared__ float redS[16][8];
  const int t = threadIdx.x, l = t & 63, w = t >> 6;
  const int lr = l & 15, lk = l >> 4;
  const int rt = blockIdx.x, h = blockIdx.y, b = blockIdx.z;
  const int bh = b * 16 + h;
  const int r0 = rt * 16;
  const size_t kvbase = (size_t)bh << 16;  // bh * 1024 * 64
  const float NEG = -3.402823466e38f;

  // Q fragment (B-operand): col lr -> q row r0+lr, k-octet lk
  bfx8 aq0 = *(const bfx8*)&q[kvbase + ((size_t)(r0 + lr) << 6) + lk * 8];
  bfx8 aq1 = *(const bfx8*)&q[kvbase + ((size_t)(r0 + lr) << 6) + 32 + lk * 8];

  const unsigned char* mb = msk + b * 1024;
  const bool rowok = mb[r0 + lr] != 0;

  // ---- phase 1: K chunks (128 rows / 16KB), 2-phase pipeline ----
  f32x4 sc[8];
  // prologue: stage chunk 0 into buf 0
  #pragma unroll
  for (int s = 0; s < 2; s++) {
    int o = s * 8192 + t * 16;
    int row = o >> 7, slot = (o >> 4) & 7;
    gload_lds16(kmat + kvbase + ((size_t)row << 6) + ((slot ^ (row & 7)) << 3),
                (char*)tile[0] + s * 8192 + w * 1024);
  }
  __syncthreads();
  #pragma unroll
  for (int c = 0; c < 8; c++) {
    if (c < 7) {
      #pragma unroll
      for (int s = 0; s < 2; s++) {
        int o = s * 8192 + t * 16;
        int row = o >> 7, slot = (o >> 4) & 7;
        gload_lds16(kmat + kvbase + ((size_t)((c + 1) * 128 + row) << 6) +
                        ((slot ^ (row & 7)) << 3),
                    (char*)tile[(c + 1) & 1] + s * 8192 + w * 1024);
      }
    }
    {
      int rloc = w * 16 + lr;
      int sw = rloc & 7;
      const char* base = (const char*)tile[c & 1] + rloc * 128;
      bfx8 bk0 = *(const bfx8*)(base + ((lk ^ sw) << 4));
      bfx8 bk1 = *(const bfx8*)(base + (((lk + 4) ^ sw) << 4));
      f32x4 a = {};
      a = __builtin_amdgcn_mfma_f32_16x16x32_bf16(bk0, aq0, a, 0, 0, 0);
      a = __builtin_amdgcn_mfma_f32_16x16x32_bf16(bk1, aq1, a, 0, 0, 0);
      // mask + scale in-loop (hides under next-chunk DMA)
      unsigned cm = *(const unsigned*)&mb[c * 128 + w * 16 + 4 * lk];
      #pragma unroll
      for (int i = 0; i < 4; i++) {
        bool ok = rowok && (((cm >> (8 * i)) & 0xffu) != 0u);
        sc[c][i] = ok ? a[i] * 0.03125f : NEG;
      }
    }
    if (c < 7) __syncthreads();
  }

  // prefetch V chunk 0 into buf 0 (tile[0] free since barrier after c=6);
  // latency hides under softmax.
  #pragma unroll
  for (int s = 0; s < 2; s++) {
    int o = s * 8192 + t * 16;
    int vrow = o >> 8, slot = (o >> 4) & 15;
    gload_lds16(vT + kvbase + ((size_t)vrow << 10) + ((slot ^ (vrow & 7)) << 3),
                (char*)tile[0] + s * 8192 + w * 1024);
  }

  // ---- phase 2: softmax over k (row = lr, spread over 8 waves) ----
  float m = NEG;
  #pragma unroll
  for (int f = 0; f < 8; f++)
    #pragma unroll
    for (int i = 0; i < 4; i++) m = fmaxf(m, sc[f][i]);
  m = fmaxf(m, __shfl_xor(m, 16));
  m = fmaxf(m, __shfl_xor(m, 32));
  if (lk == 0) redM[lr][w] = m;
  __syncthreads();
  {
    float4 m0 = *(const float4*)&redM[lr][0];
    float4 m1 = *(const float4*)&redM[lr][4];
    m = fmaxf(fmaxf(fmaxf(m0.x, m0.y), fmaxf(m0.z, m0.w)),
              fmaxf(fmaxf(m1.x, m1.y), fmaxf(m1.z, m1.w)));
  }
  float s = 0.f;
  #pragma unroll
  for (int f = 0; f < 8; f++)
    #pragma unroll
    for (int i = 0; i < 4; i++) { sc[f][i] = __expf(sc[f][i] - m); s += sc[f][i]; }
  s += __shfl_xor(s, 16);
  s += __shfl_xor(s, 32);
  if (lk == 0) redS[lr][w] = s;
  __syncthreads();
  float inv;
  {
    float4 s0 = *(const float4*)&redS[lr][0];
    float4 s1 = *(const float4*)&redS[lr][4];
    inv = 1.0f / (s0.x + s0.y + s0.z + s0.w + s1.x + s1.y + s1.z + s1.w);
  }

  // ---- P (bf16) -> LDS, swizzled: row lr, col c*128 + w*16 + 4lk ----
  #pragma unroll
  for (int c = 0; c < 8; c++) {
    union { ushort u[4]; uint2 d; } pk;
    pk.u[0] = (ushort)f2bfbits(sc[c][0] * inv);
    pk.u[1] = (ushort)f2bfbits(sc[c][1] * inv);
    pk.u[2] = (ushort)f2bfbits(sc[c][2] * inv);
    pk.u[3] = (ushort)f2bfbits(sc[c][3] * inv);
    int slot_lin = c * 16 + w * 2 + (lk >> 1);
    int addr = lr * 2048 + ((slot_lin ^ (lr & 7)) << 4) + ((lk & 1) << 3);
    *(uint2*)((char*)P + addr) = pk.d;
  }
  __syncthreads();   // P visible; V chunk 0 also drained

  // ---- phase 3: ctx = P @ V, chunks of 128 cols, 2-phase pipeline ----
  const int dg = w & 3, ch = w >> 2;
  const int vr = dg * 16 + lr;
  const int swv = vr & 7;
  f32x4 o0 = {}, o1 = {};
  #pragma unroll
  for (int c = 0; c < 8; c++) {
    if (c < 7) {
      #pragma unroll
      for (int s = 0; s < 2; s++) {
        int o = s * 8192 + t * 16;
        int vrow = o >> 8, slot = (o >> 4) & 15;
        gload_lds16(vT + kvbase + ((size_t)vrow << 10) + (c + 1) * 128 +
                        ((slot ^ (vrow & 7)) << 3),
                    (char*)tile[(c + 1) & 1] + s * 8192 + w * 1024);
      }
    }
    #pragma unroll
    for (int k2 = 0; k2 < 2; k2++) {
      int ksl = ch * 2 + k2;
      int slot_lin = c * 16 + ksl * 4 + lk;
      bfx8 pa = *(const bfx8*)((const char*)P + lr * 2048 +
                               ((slot_lin ^ (lr & 7)) << 4));
      int vslot = ksl * 4 + lk;
      bfx8 bv = *(const bfx8*)((const char*)tile[c & 1] + vr * 256 +
                               ((vslot ^ swv) << 4));
      if (k2) o1 = __builtin_amdgcn_mfma_f32_16x16x32_bf16(pa, bv, o1, 0, 0, 0);
      else    o0 = __builtin_amdgcn_mfma_f32_16x16x32_bf16(pa, bv, o0, 0, 0, 0);
    }
    if (c < 7) __syncthreads();
  }

  // ---- cross-wave (col-half) reduce + ctx store; reuse tile[0] as scratch ----
  f32x4 oo;
  #pragma unroll
  for (int i = 0; i < 4; i++) oo[i] = o0[i] + o1[i];
  f32x4* redC = (f32x4*)&tile[0][0];    // 4KB, free since barrier after c=6
  if (w >= 4) redC[(w - 4) * 64 + l] = oo;
  __syncthreads();
  if (w < 4) {
    f32x4 op = redC[w * 64 + l];
    #pragma unroll
    for (int i = 0; i < 4; i++) {
      float v = oo[i] + op[i];
      ctx[(((size_t)b << 10) + r0 + 4 * lk + i) * 1024 + (h << 6) + (w << 4) + lr] =
          f2bfbits(v);
    }
  }

  // ---- stream attn out from P: full-line contiguous stores (2 rows/wave) ----
  #pragma unroll
  for (int rg = 0; rg < 2; rg++) {
    int row = w * 2 + rg;
    float* arow = attn + ((size_t)bh * 1024 + r0 + row) * 1024;
    int swr = row & 7;
    #pragma unroll
    for (int it = 0; it < 4; it++) {
      int ci = it * 64 + l;              // 16B output chunk (4 f32)
      uint2 d = *(const uint2*)((const char*)P + row * 2048 +
                                (((ci >> 1) ^ swr) << 4) + ((ci & 1) << 3));
      float4 o;
      o.x = __uint_as_float(d.x << 16);
      o.y = __uint_as_float(d.x & 0xffff0000u);
      o.z = __uint_as_float(d.y << 16);
      o.w = __uint_as_float(d.y & 0xffff0000u);
      *(float4*)&arow[ci * 4] = o;
    }
  }
}

// ---------------- launch ----------------

extern "C" void kernel_launch(void* const* d_in, const int* in_sizes, int n_in,
                              void* d_out, int out_size, void* d_ws, size_t ws_size,
                              hipStream_t stream) {
  const float* x    = (const float*)d_in[0];
  const int*   mask = (const int*)d_in[1];
  const float* Wqkv = (const float*)d_in[2];
  const float* bqkv = (const float*)d_in[3];
  const float* Wout = (const float*)d_in[4];
  const float* bout = (const float*)d_in[5];
  float* out  = (float*)d_out;
  float* attn = out + (size_t)4 * 1024 * 1024;

  char* ws = (char*)d_ws;
  short* xb    = (short*)(ws);                  //  8 MB  x bf16 [4096][1024]
  short* wqkvT = (short*)(ws + 8388608);        //  6 MB  [3072][1024]
  short* woutT = (short*)(ws + 14680064);       //  2 MB  [1024][1024]
  short* qws   = (short*)(ws + 16777216);       //  8 MB  [64][1024][64]
  short* kws   = (short*)(ws + 25165824);       //  8 MB  [64][1024][64]
  short* vTws  = (short*)(ws + 33554432);       //  8 MB  [64][64][1024]
  short* ctx   = (short*)(ws + 41943040);       //  8 MB  [4096][1024]
  unsigned char* msk = (unsigned char*)(ws + 50331648);  // 4 KB

  k_cvt_x<<<4096, 256, 0, stream>>>(x, xb);
  k_transpose<<<dim3(96, 32), dim3(32, 8), 0, stream>>>(Wqkv, wqkvT, 1024, 3072);
  k_transpose<<<dim3(32, 32), dim3(32, 8), 0, stream>>>(Wout, woutT, 1024, 1024);
  k_mask<<<16, 256, 0, stream>>>(mask, msk);
  k_gemm<<<dim3(24, 32), 256, 0, stream>>>(xb, wqkvT, bqkv, 1024, 0,
                                           qws, kws, vTws, nullptr);
  k_attn<<<dim3(64, 16, 4), 512, 0, stream>>>(qws, kws, vTws, msk, attn, ctx);
  k_gemm<<<dim3(8, 32), 256, 0, stream>>>(ctx, woutT, bout, 1024, 1,
                                          nullptr, nullptr, nullptr, out);
}

// Round 5
// 175.918 us; speedup vs baseline: 1.3351x; 1.3351x over previous
//
#include <hip/hip_runtime.h>
#include <stdint.h>

#define DEV static __device__ __forceinline__

typedef __attribute__((ext_vector_type(8))) __bf16 bfx8;
typedef __attribute__((ext_vector_type(4))) float f32x4;

DEV short f2bfbits(float f) {
  union { float f; unsigned u; } v; v.f = f;
  unsigned r = v.u + 0x7fffu + ((v.u >> 16) & 1u);
  return (short)(r >> 16);
}

DEV void gload_lds16(const void* g, void* lds) {
  __builtin_amdgcn_global_load_lds(
      (const __attribute__((address_space(1))) void*)g,
      (__attribute__((address_space(3))) void*)lds, 16, 0, 0);
}

// ---------------- prep kernels ----------------

__global__ void k_cvt_x(const float* __restrict__ src, short* __restrict__ dst) {
  int i = blockIdx.x * 256 + threadIdx.x;            // 4 floats per thread
  float4 v = ((const float4*)src)[i];
  union { short s[4]; uint64_t u; } o;
  o.s[0] = f2bfbits(v.x); o.s[1] = f2bfbits(v.y);
  o.s[2] = f2bfbits(v.z); o.s[3] = f2bfbits(v.w);
  ((uint64_t*)dst)[i] = o.u;
}

// src [R][C] f32 -> dst [C][R] bf16
__global__ void k_transpose(const float* __restrict__ src, short* __restrict__ dst,
                            int R, int C) {
  __shared__ float tile[32][33];
  int c0 = blockIdx.x * 32, r0 = blockIdx.y * 32;
  int tx = threadIdx.x, ty = threadIdx.y;            // block (32,8)
  #pragma unroll
  for (int j = 0; j < 32; j += 8)
    tile[ty + j][tx] = src[(size_t)(r0 + ty + j) * C + c0 + tx];
  __syncthreads();
  #pragma unroll
  for (int j = 0; j < 32; j += 8)
    dst[(size_t)(c0 + ty + j) * R + r0 + tx] = f2bfbits(tile[tx][ty + j]);
}

// msk[b][n]: n==0 -> 1 else mask[b][n-1]
__global__ void k_mask(const int* __restrict__ mask, unsigned char* __restrict__ msk) {
  int i = blockIdx.x * 256 + threadIdx.x;            // [0, 4096)
  int b = i >> 10, n = i & 1023;
  msk[i] = (n == 0) ? (unsigned char)1 : (unsigned char)(mask[b * 1023 + n - 1] != 0);
}

// ---------------- GEMM: C = A[M][K] @ Bt[N][K]^T + bias ----------------
// mode 0: scatter q/k/v into MFMA-FRAGMENT layouts (bf16):
//   q/kfrag: [bh][blk=n>>4][half=d>>5][lane=(lk<<4)|(n&15)][8]  (2KB per blk)
//   vfrag:   [bh][db=d>>4][jj=n>>5][lane=(lk<<4)|(d&15)][8]     (1KB per jj)
// mode 1: f32 out + bias, N=1024.
__global__ __launch_bounds__(256)
void k_gemm(const short* __restrict__ A, const short* __restrict__ Bt,
            const float* __restrict__ bias, int K, int mode,
            short* __restrict__ qf, short* __restrict__ kf,
            short* __restrict__ vf, float* __restrict__ outF) {
  __shared__ short As[128 * 32];
  __shared__ short Bs[128 * 32];
  const int t = threadIdx.x;
  const int l = t & 63, w = t >> 6;
  const int lr = l & 15, lk = l >> 4;
  const int m0 = blockIdx.y * 128, n0 = blockIdx.x * 128;
  const int wr = (w >> 1) * 64, wc = (w & 1) * 64;
  f32x4 acc[4][4] = {};

  const int srow = t >> 2;
  const int sc8 = (t & 3) * 8;
  const size_t aoff1 = (size_t)(m0 + srow) * K + sc8;
  const size_t aoff2 = (size_t)(m0 + srow + 64) * K + sc8;
  const size_t boff1 = (size_t)(n0 + srow) * K + sc8;
  const size_t boff2 = (size_t)(n0 + srow + 64) * K + sc8;
  short* asd1 = As + (t & ~63) * 8;
  short* asd2 = As + (t & ~63) * 8 + 2048;
  short* bsd1 = Bs + (t & ~63) * 8;
  short* bsd2 = Bs + (t & ~63) * 8 + 2048;

  for (int k0 = 0; k0 < K; k0 += 32) {
    gload_lds16(A + aoff1 + k0, asd1);
    gload_lds16(A + aoff2 + k0, asd2);
    gload_lds16(Bt + boff1 + k0, bsd1);
    gload_lds16(Bt + boff2 + k0, bsd2);
    __syncthreads();
    bfx8 af[4], bf[4];
    #pragma unroll
    for (int m = 0; m < 4; m++)
      af[m] = *(const bfx8*)&As[(wr + m * 16 + lr) * 32 + lk * 8];
    #pragma unroll
    for (int n = 0; n < 4; n++)
      bf[n] = *(const bfx8*)&Bs[(wc + n * 16 + lr) * 32 + lk * 8];
    #pragma unroll
    for (int m = 0; m < 4; m++)
      #pragma unroll
      for (int n = 0; n < 4; n++)
        acc[m][n] = __builtin_amdgcn_mfma_f32_16x16x32_bf16(af[m], bf[n], acc[m][n], 0, 0, 0);
    __syncthreads();
  }

  if (mode == 0) {
    #pragma unroll
    for (int m = 0; m < 4; m++) {
      int grb = m0 + wr + m * 16 + 4 * lk;
      #pragma unroll
      for (int n = 0; n < 4; n++) {
        int gc = n0 + wc + n * 16 + lr;
        float bv = bias[gc];
        int which = gc >> 10, rem = gc & 1023;
        int hh = rem >> 6, dd = rem & 63;
        #pragma unroll
        for (int i = 0; i < 4; i++) {
          int gr = grb + i;
          int bb = gr >> 10, nn = gr & 1023;
          size_t bh = (size_t)(bb * 16 + hh);
          short val = f2bfbits(acc[m][n][i] + bv);
          if (which < 2) {
            size_t idx = ((bh * 64 + (nn >> 4)) << 10) + ((size_t)(dd >> 5) << 9) +
                         ((((dd >> 3) & 3) * 16 + (nn & 15)) << 3) + (dd & 7);
            if (which == 0) qf[idx] = val; else kf[idx] = val;
          } else {
            size_t idx = (((bh * 4 + (dd >> 4)) * 32 + (nn >> 5)) << 9) +
                         ((((nn >> 3) & 3) * 16 + (dd & 15)) << 3) + (nn & 7);
            vf[idx] = val;
          }
        }
      }
    }
  } else {
    #pragma unroll
    for (int m = 0; m < 4; m++) {
      #pragma unroll
      for (int n = 0; n < 4; n++) {
        int gc = n0 + wc + n * 16 + lr;
        float bv = bias[gc];
        #pragma unroll
        for (int i = 0; i < 4; i++) {
          int gr = m0 + wr + m * 16 + 4 * lk + i;
          outF[(size_t)gr * 1024 + gc] = acc[m][n][i] + bv;
        }
      }
    }
  }
}

// ---------------- fused attention v5 ----------------
// WG = (b,h) x 16 q-rows, 8 waves (512 thr). NO staging: all Q/K/V operands
// read directly as lane-contiguous 1KB global loads from fragment layouts
// (L2-resident; XCD-chunked swizzle pins each bh to one XCD). Logits in
// registers (swapped QK^T); P bf16 in LDS (swizzled); attn streamed as 1KB
// lines BEFORE PV so the write overlaps PV compute.
__global__ __launch_bounds__(512, 4)
void k_attn(const short* __restrict__ qf_, const short* __restrict__ kf_,
            const short* __restrict__ vf_, const unsigned char* __restrict__ msk,
            float* __restrict__ attn, short* __restrict__ ctx) {
  __shared__ short P[16 * 1024];      // 32KB bf16 P, swizzled 16B slots
  __shared__ float redM[16][8];
  __shared__ float redS[16][8];
  __shared__ f32x4 redC[256];         // 4KB ctx cross-wave reduce
  const int t = threadIdx.x, l = t & 63, w = t >> 6;
  const int lr = l & 15, lk = l >> 4;
  // XCD-chunked swizzle: 4096 WGs = 8 XCDs x 512; 64 consecutive = one (b,h)
  const int wg = ((blockIdx.x & 7) << 9) | (blockIdx.x >> 3);
  const int rt = wg & 63, h = (wg >> 6) & 15, b = wg >> 10;
  const int bh = b * 16 + h;
  const int r0 = rt * 16;
  const float NEG = -3.402823466e38f;

  // Q fragment: lane l -> q row r0+lr, k-octet lk (+half*32)
  const short* qf = qf_ + ((size_t)(bh * 64 + rt) << 10);
  bfx8 aq0 = *(const bfx8*)&qf[l * 8];
  bfx8 aq1 = *(const bfx8*)&qf[512 + l * 8];

  const unsigned char* mb = msk + b * 1024;
  const bool rowok = mb[r0 + lr] != 0;

  // ---- phase 1: QK^T, wave w owns cols w*128..w*128+127 ----
  f32x4 sc[8];
  #pragma unroll
  for (int cc = 0; cc < 8; cc++) {
    const short* kfp = kf_ + ((size_t)(bh * 64 + w * 8 + cc) << 10);
    bfx8 bk0 = *(const bfx8*)&kfp[l * 8];
    bfx8 bk1 = *(const bfx8*)&kfp[512 + l * 8];
    f32x4 a = {};
    a = __builtin_amdgcn_mfma_f32_16x16x32_bf16(bk0, aq0, a, 0, 0, 0);
    a = __builtin_amdgcn_mfma_f32_16x16x32_bf16(bk1, aq1, a, 0, 0, 0);
    unsigned cm = *(const unsigned*)&mb[w * 128 + cc * 16 + 4 * lk];
    #pragma unroll
    for (int i = 0; i < 4; i++) {
      bool ok = rowok && (((cm >> (8 * i)) & 0xffu) != 0u);
      sc[cc][i] = ok ? a[i] * 0.03125f : NEG;
    }
  }

  // ---- phase 2: softmax over k (row = lr) ----
  float m = NEG;
  #pragma unroll
  for (int f = 0; f < 8; f++)
    #pragma unroll
    for (int i = 0; i < 4; i++) m = fmaxf(m, sc[f][i]);
  m = fmaxf(m, __shfl_xor(m, 16));
  m = fmaxf(m, __shfl_xor(m, 32));
  if (lk == 0) redM[lr][w] = m;
  __syncthreads();
  {
    float4 m0 = *(const float4*)&redM[lr][0];
    float4 m1 = *(const float4*)&redM[lr][4];
    m = fmaxf(fmaxf(fmaxf(m0.x, m0.y), fmaxf(m0.z, m0.w)),
              fmaxf(fmaxf(m1.x, m1.y), fmaxf(m1.z, m1.w)));
  }
  float s = 0.f;
  #pragma unroll
  for (int f = 0; f < 8; f++)
    #pragma unroll
    for (int i = 0; i < 4; i++) { sc[f][i] = __expf(sc[f][i] - m); s += sc[f][i]; }
  s += __shfl_xor(s, 16);
  s += __shfl_xor(s, 32);
  if (lk == 0) redS[lr][w] = s;
  __syncthreads();
  float inv;
  {
    float4 s0 = *(const float4*)&redS[lr][0];
    float4 s1 = *(const float4*)&redS[lr][4];
    inv = 1.0f / (s0.x + s0.y + s0.z + s0.w + s1.x + s1.y + s1.z + s1.w);
  }

  // ---- P (bf16) -> LDS, swizzled: row lr, col w*128 + cc*16 + 4lk ----
  #pragma unroll
  for (int cc = 0; cc < 8; cc++) {
    union { ushort u[4]; uint2 d; } pk;
    pk.u[0] = (ushort)f2bfbits(sc[cc][0] * inv);
    pk.u[1] = (ushort)f2bfbits(sc[cc][1] * inv);
    pk.u[2] = (ushort)f2bfbits(sc[cc][2] * inv);
    pk.u[3] = (ushort)f2bfbits(sc[cc][3] * inv);
    int slot_lin = w * 16 + cc * 2 + (lk >> 1);
    int addr = lr * 2048 + ((slot_lin ^ (lr & 7)) << 4) + ((lk & 1) << 3);
    *(uint2*)((char*)P + addr) = pk.d;
  }
  __syncthreads();   // P visible to all waves

  // ---- stream attn out NOW (overlaps PV below): 2 rows/wave, 1KB lines ----
  #pragma unroll
  for (int rg = 0; rg < 2; rg++) {
    int row = w * 2 + rg;
    float* arow = attn + ((size_t)bh * 1024 + r0 + row) * 1024;
    int swr = row & 7;
    #pragma unroll
    for (int it = 0; it < 4; it++) {
      int ci = it * 64 + l;              // 16B output chunk (4 f32)
      uint2 d = *(const uint2*)((const char*)P + row * 2048 +
                                (((ci >> 1) ^ swr) << 4) + ((ci & 1) << 3));
      float4 o;
      o.x = __uint_as_float(d.x << 16);
      o.y = __uint_as_float(d.x & 0xffff0000u);
      o.z = __uint_as_float(d.y << 16);
      o.w = __uint_as_float(d.y & 0xffff0000u);
      *(float4*)&arow[ci * 4] = o;
    }
  }

  // ---- phase 3: ctx = P @ V; wave w: dim-grp dg=w&3, col-half ch=w>>2 ----
  const int dg = w & 3, ch = w >> 2;
  f32x4 o0 = {}, o1 = {};
  #pragma unroll
  for (int j = 0; j < 16; j++) {
    int jj = ch * 16 + j;
    const short* vfp = vf_ + (((size_t)(bh * 4 + dg) * 32 + jj) << 9);
    bfx8 bv = *(const bfx8*)&vfp[l * 8];
    int slot_lin = jj * 4 + lk;
    bfx8 pa = *(const bfx8*)((const char*)P + lr * 2048 +
                             ((slot_lin ^ (lr & 7)) << 4));
    if (j & 1) o1 = __builtin_amdgcn_mfma_f32_16x16x32_bf16(pa, bv, o1, 0, 0, 0);
    else       o0 = __builtin_amdgcn_mfma_f32_16x16x32_bf16(pa, bv, o0, 0, 0, 0);
  }

  // ---- cross-wave (col-half) reduce + ctx store ----
  f32x4 oo;
  #pragma unroll
  for (int i = 0; i < 4; i++) oo[i] = o0[i] + o1[i];
  if (w >= 4) redC[(w - 4) * 64 + l] = oo;
  __syncthreads();
  if (w < 4) {
    f32x4 op = redC[w * 64 + l];
    #pragma unroll
    for (int i = 0; i < 4; i++) {
      float v = oo[i] + op[i];
      ctx[(((size_t)b << 10) + r0 + 4 * lk + i) * 1024 + (h << 6) + (w << 4) + lr] =
          f2bfbits(v);
    }
  }
}

// ---------------- launch ----------------

extern "C" void kernel_launch(void* const* d_in, const int* in_sizes, int n_in,
                              void* d_out, int out_size, void* d_ws, size_t ws_size,
                              hipStream_t stream) {
  const float* x    = (const float*)d_in[0];
  const int*   mask = (const int*)d_in[1];
  const float* Wqkv = (const float*)d_in[2];
  const float* bqkv = (const float*)d_in[3];
  const float* Wout = (const float*)d_in[4];
  const float* bout = (const float*)d_in[5];
  float* out  = (float*)d_out;
  float* attn = out + (size_t)4 * 1024 * 1024;

  char* ws = (char*)d_ws;
  short* xb    = (short*)(ws);                  //  8 MB  x bf16 [4096][1024]
  short* wqkvT = (short*)(ws + 8388608);        //  6 MB  [3072][1024]
  short* woutT = (short*)(ws + 14680064);       //  2 MB  [1024][1024]
  short* qfr   = (short*)(ws + 16777216);       //  8 MB  Q fragments
  short* kfr   = (short*)(ws + 25165824);       //  8 MB  K fragments
  short* vfr   = (short*)(ws + 33554432);       //  8 MB  V fragments
  short* ctx   = (short*)(ws + 41943040);       //  8 MB  [4096][1024]
  unsigned char* msk = (unsigned char*)(ws + 50331648);  // 4 KB

  k_cvt_x<<<4096, 256, 0, stream>>>(x, xb);
  k_transpose<<<dim3(96, 32), dim3(32, 8), 0, stream>>>(Wqkv, wqkvT, 1024, 3072);
  k_transpose<<<dim3(32, 32), dim3(32, 8), 0, stream>>>(Wout, woutT, 1024, 1024);
  k_mask<<<16, 256, 0, stream>>>(mask, msk);
  k_gemm<<<dim3(24, 32), 256, 0, stream>>>(xb, wqkvT, bqkv, 1024, 0,
                                           qfr, kfr, vfr, nullptr);
  k_attn<<<4096, 512, 0, stream>>>(qfr, kfr, vfr, msk, attn, ctx);
  k_gemm<<<dim3(8, 32), 256, 0, stream>>>(ctx, woutT, bout, 1024, 1,
                                          nullptr, nullptr, nullptr, out);
}

// Round 6
// 149.143 us; speedup vs baseline: 1.5747x; 1.1795x over previous
//
#include <hip/hip_runtime.h>
#include <stdint.h>

#define DEV static __device__ __forceinline__

typedef __attribute__((ext_vector_type(8))) __bf16 bfx8;
typedef __attribute__((ext_vector_type(4))) float f32x4;

DEV short f2bfbits(float f) {
  union { float f; unsigned u; } v; v.f = f;
  unsigned r = v.u + 0x7fffu + ((v.u >> 16) & 1u);
  return (short)(r >> 16);
}

DEV void gload_lds16(const void* g, void* lds) {
  __builtin_amdgcn_global_load_lds(
      (const __attribute__((address_space(1))) void*)g,
      (__attribute__((address_space(3))) void*)lds, 16, 0, 0);
}

// ---------------- prep: x->bf16 (blocks 0..4095) + mask (4096..4111) ----------------
__global__ void k_prep(const float* __restrict__ src, short* __restrict__ dst,
                       const int* __restrict__ mask, unsigned char* __restrict__ msk) {
  int bx = blockIdx.x;
  if (bx < 4096) {
    int i = bx * 256 + threadIdx.x;                  // 4 floats per thread
    float4 v = ((const float4*)src)[i];
    union { short s[4]; uint64_t u; } o;
    o.s[0] = f2bfbits(v.x); o.s[1] = f2bfbits(v.y);
    o.s[2] = f2bfbits(v.z); o.s[3] = f2bfbits(v.w);
    ((uint64_t*)dst)[i] = o.u;
  } else {
    int i = (bx - 4096) * 256 + threadIdx.x;         // [0, 4096)
    int b = i >> 10, n = i & 1023;
    msk[i] = (n == 0) ? (unsigned char)1 : (unsigned char)(mask[b * 1023 + n - 1] != 0);
  }
}

// both weight transposes in one launch: bx<96 -> Wqkv (C=3072), else Wout (C=1024)
__global__ void k_transpose2(const float* __restrict__ Wqkv, short* __restrict__ wqkvT,
                             const float* __restrict__ Wout, short* __restrict__ woutT) {
  __shared__ float tile[32][33];
  int bx = blockIdx.x;
  const float* src; short* dst; int C;
  if (bx < 96) { src = Wqkv; dst = wqkvT; C = 3072; }
  else         { src = Wout; dst = woutT; C = 1024; bx -= 96; }
  const int R = 1024;
  int c0 = bx * 32, r0 = blockIdx.y * 32;
  int tx = threadIdx.x, ty = threadIdx.y;            // block (32,8)
  #pragma unroll
  for (int j = 0; j < 32; j += 8)
    tile[ty + j][tx] = src[(size_t)(r0 + ty + j) * C + c0 + tx];
  __syncthreads();
  #pragma unroll
  for (int j = 0; j < 32; j += 8)
    dst[(size_t)(c0 + ty + j) * R + r0 + tx] = f2bfbits(tile[tx][ty + j]);
}

// ---------------- QKV GEMM: C = A[M][K] @ Bt[N][K]^T + bias, scatter to fragments ----
//   q/kfrag: [bh][blk=n>>4][half=d>>5][lane=(lk<<4)|(n&15)][8]  (2KB per blk)
//   vfrag:   [bh][db=d>>4][jj=n>>5][lane=(lk<<4)|(d&15)][8]     (1KB per jj)
__global__ __launch_bounds__(256)
void k_gemm(const short* __restrict__ A, const short* __restrict__ Bt,
            const float* __restrict__ bias, int K,
            short* __restrict__ qf, short* __restrict__ kf,
            short* __restrict__ vf) {
  __shared__ short As[128 * 32];
  __shared__ short Bs[128 * 32];
  const int t = threadIdx.x;
  const int l = t & 63, w = t >> 6;
  const int lr = l & 15, lk = l >> 4;
  const int m0 = blockIdx.y * 128, n0 = blockIdx.x * 128;
  const int wr = (w >> 1) * 64, wc = (w & 1) * 64;
  f32x4 acc[4][4] = {};

  const int srow = t >> 2;
  const int sc8 = (t & 3) * 8;
  const size_t aoff1 = (size_t)(m0 + srow) * K + sc8;
  const size_t aoff2 = (size_t)(m0 + srow + 64) * K + sc8;
  const size_t boff1 = (size_t)(n0 + srow) * K + sc8;
  const size_t boff2 = (size_t)(n0 + srow + 64) * K + sc8;
  short* asd1 = As + (t & ~63) * 8;
  short* asd2 = As + (t & ~63) * 8 + 2048;
  short* bsd1 = Bs + (t & ~63) * 8;
  short* bsd2 = Bs + (t & ~63) * 8 + 2048;

  for (int k0 = 0; k0 < K; k0 += 32) {
    gload_lds16(A + aoff1 + k0, asd1);
    gload_lds16(A + aoff2 + k0, asd2);
    gload_lds16(Bt + boff1 + k0, bsd1);
    gload_lds16(Bt + boff2 + k0, bsd2);
    __syncthreads();
    bfx8 af[4], bf[4];
    #pragma unroll
    for (int m = 0; m < 4; m++)
      af[m] = *(const bfx8*)&As[(wr + m * 16 + lr) * 32 + lk * 8];
    #pragma unroll
    for (int n = 0; n < 4; n++)
      bf[n] = *(const bfx8*)&Bs[(wc + n * 16 + lr) * 32 + lk * 8];
    #pragma unroll
    for (int m = 0; m < 4; m++)
      #pragma unroll
      for (int n = 0; n < 4; n++)
        acc[m][n] = __builtin_amdgcn_mfma_f32_16x16x32_bf16(af[m], bf[n], acc[m][n], 0, 0, 0);
    __syncthreads();
  }

  #pragma unroll
  for (int m = 0; m < 4; m++) {
    int grb = m0 + wr + m * 16 + 4 * lk;
    #pragma unroll
    for (int n = 0; n < 4; n++) {
      int gc = n0 + wc + n * 16 + lr;
      float bv = bias[gc];
      int which = gc >> 10, rem = gc & 1023;
      int hh = rem >> 6, dd = rem & 63;
      #pragma unroll
      for (int i = 0; i < 4; i++) {
        int gr = grb + i;
        int bb = gr >> 10, nn = gr & 1023;
        size_t bh = (size_t)(bb * 16 + hh);
        short val = f2bfbits(acc[m][n][i] + bv);
        if (which < 2) {
          size_t idx = ((bh * 64 + (nn >> 4)) << 10) + ((size_t)(dd >> 5) << 9) +
                       ((((dd >> 3) & 3) * 16 + (nn & 15)) << 3) + (dd & 7);
          if (which == 0) qf[idx] = val; else kf[idx] = val;
        } else {
          size_t idx = (((bh * 4 + (dd >> 4)) * 32 + (nn >> 5)) << 9) +
                       ((((nn >> 3) & 3) * 16 + (dd & 15)) << 3) + (nn & 7);
          vf[idx] = val;
        }
      }
    }
  }
}

// ---------------- out GEMM: BM=128, BN=64 -> 512 WGs (2/CU) ----------------
__global__ __launch_bounds__(256)
void k_gemm_out(const short* __restrict__ A, const short* __restrict__ Bt,
                const float* __restrict__ bias, float* __restrict__ outF) {
  __shared__ short As[128 * 32];
  __shared__ short Bs[64 * 32];
  const int K = 1024;
  const int t = threadIdx.x;
  const int l = t & 63, w = t >> 6;
  const int lr = l & 15, lk = l >> 4;
  const int m0 = blockIdx.y * 128, n0 = blockIdx.x * 64;
  const int wr = (w >> 1) * 64, wc = (w & 1) * 32;
  f32x4 acc[4][2] = {};

  const int srow = t >> 2;
  const int sc8 = (t & 3) * 8;
  const size_t aoff1 = (size_t)(m0 + srow) * K + sc8;
  const size_t aoff2 = (size_t)(m0 + srow + 64) * K + sc8;
  const size_t boff1 = (size_t)(n0 + srow) * K + sc8;
  short* asd1 = As + (t & ~63) * 8;
  short* asd2 = As + (t & ~63) * 8 + 2048;
  short* bsd1 = Bs + (t & ~63) * 8;

  for (int k0 = 0; k0 < K; k0 += 32) {
    gload_lds16(A + aoff1 + k0, asd1);
    gload_lds16(A + aoff2 + k0, asd2);
    gload_lds16(Bt + boff1 + k0, bsd1);
    __syncthreads();
    bfx8 af[4], bf[2];
    #pragma unroll
    for (int m = 0; m < 4; m++)
      af[m] = *(const bfx8*)&As[(wr + m * 16 + lr) * 32 + lk * 8];
    #pragma unroll
    for (int n = 0; n < 2; n++)
      bf[n] = *(const bfx8*)&Bs[(wc + n * 16 + lr) * 32 + lk * 8];
    #pragma unroll
    for (int m = 0; m < 4; m++)
      #pragma unroll
      for (int n = 0; n < 2; n++)
        acc[m][n] = __builtin_amdgcn_mfma_f32_16x16x32_bf16(af[m], bf[n], acc[m][n], 0, 0, 0);
    __syncthreads();
  }

  #pragma unroll
  for (int m = 0; m < 4; m++) {
    #pragma unroll
    for (int n = 0; n < 2; n++) {
      int gc = n0 + wc + n * 16 + lr;
      float bv = bias[gc];
      #pragma unroll
      for (int i = 0; i < 4; i++) {
        int gr = m0 + wr + m * 16 + 4 * lk + i;
        outF[(size_t)gr * 1024 + gc] = acc[m][n][i] + bv;
      }
    }
  }
}

// ---------------- fused attention v5 (unchanged) ----------------
__global__ __launch_bounds__(512, 4)
void k_attn(const short* __restrict__ qf_, const short* __restrict__ kf_,
            const short* __restrict__ vf_, const unsigned char* __restrict__ msk,
            float* __restrict__ attn, short* __restrict__ ctx) {
  __shared__ short P[16 * 1024];      // 32KB bf16 P, swizzled 16B slots
  __shared__ float redM[16][8];
  __shared__ float redS[16][8];
  __shared__ f32x4 redC[256];         // 4KB ctx cross-wave reduce
  const int t = threadIdx.x, l = t & 63, w = t >> 6;
  const int lr = l & 15, lk = l >> 4;
  // XCD-chunked swizzle: 4096 WGs = 8 XCDs x 512; 64 consecutive = one (b,h)
  const int wg = ((blockIdx.x & 7) << 9) | (blockIdx.x >> 3);
  const int rt = wg & 63, h = (wg >> 6) & 15, b = wg >> 10;
  const int bh = b * 16 + h;
  const int r0 = rt * 16;
  const float NEG = -3.402823466e38f;

  // Q fragment: lane l -> q row r0+lr, k-octet lk (+half*32)
  const short* qf = qf_ + ((size_t)(bh * 64 + rt) << 10);
  bfx8 aq0 = *(const bfx8*)&qf[l * 8];
  bfx8 aq1 = *(const bfx8*)&qf[512 + l * 8];

  const unsigned char* mb = msk + b * 1024;
  const bool rowok = mb[r0 + lr] != 0;

  // ---- phase 1: QK^T, wave w owns cols w*128..w*128+127 ----
  f32x4 sc[8];
  #pragma unroll
  for (int cc = 0; cc < 8; cc++) {
    const short* kfp = kf_ + ((size_t)(bh * 64 + w * 8 + cc) << 10);
    bfx8 bk0 = *(const bfx8*)&kfp[l * 8];
    bfx8 bk1 = *(const bfx8*)&kfp[512 + l * 8];
    f32x4 a = {};
    a = __builtin_amdgcn_mfma_f32_16x16x32_bf16(bk0, aq0, a, 0, 0, 0);
    a = __builtin_amdgcn_mfma_f32_16x16x32_bf16(bk1, aq1, a, 0, 0, 0);
    unsigned cm = *(const unsigned*)&mb[w * 128 + cc * 16 + 4 * lk];
    #pragma unroll
    for (int i = 0; i < 4; i++) {
      bool ok = rowok && (((cm >> (8 * i)) & 0xffu) != 0u);
      sc[cc][i] = ok ? a[i] * 0.03125f : NEG;
    }
  }

  // ---- phase 2: softmax over k (row = lr) ----
  float m = NEG;
  #pragma unroll
  for (int f = 0; f < 8; f++)
    #pragma unroll
    for (int i = 0; i < 4; i++) m = fmaxf(m, sc[f][i]);
  m = fmaxf(m, __shfl_xor(m, 16));
  m = fmaxf(m, __shfl_xor(m, 32));
  if (lk == 0) redM[lr][w] = m;
  __syncthreads();
  {
    float4 m0 = *(const float4*)&redM[lr][0];
    float4 m1 = *(const float4*)&redM[lr][4];
    m = fmaxf(fmaxf(fmaxf(m0.x, m0.y), fmaxf(m0.z, m0.w)),
              fmaxf(fmaxf(m1.x, m1.y), fmaxf(m1.z, m1.w)));
  }
  float s = 0.f;
  #pragma unroll
  for (int f = 0; f < 8; f++)
    #pragma unroll
    for (int i = 0; i < 4; i++) { sc[f][i] = __expf(sc[f][i] - m); s += sc[f][i]; }
  s += __shfl_xor(s, 16);
  s += __shfl_xor(s, 32);
  if (lk == 0) redS[lr][w] = s;
  __syncthreads();
  float inv;
  {
    float4 s0 = *(const float4*)&redS[lr][0];
    float4 s1 = *(const float4*)&redS[lr][4];
    inv = 1.0f / (s0.x + s0.y + s0.z + s0.w + s1.x + s1.y + s1.z + s1.w);
  }

  // ---- P (bf16) -> LDS, swizzled: row lr, col w*128 + cc*16 + 4lk ----
  #pragma unroll
  for (int cc = 0; cc < 8; cc++) {
    union { ushort u[4]; uint2 d; } pk;
    pk.u[0] = (ushort)f2bfbits(sc[cc][0] * inv);
    pk.u[1] = (ushort)f2bfbits(sc[cc][1] * inv);
    pk.u[2] = (ushort)f2bfbits(sc[cc][2] * inv);
    pk.u[3] = (ushort)f2bfbits(sc[cc][3] * inv);
    int slot_lin = w * 16 + cc * 2 + (lk >> 1);
    int addr = lr * 2048 + ((slot_lin ^ (lr & 7)) << 4) + ((lk & 1) << 3);
    *(uint2*)((char*)P + addr) = pk.d;
  }
  __syncthreads();   // P visible to all waves

  // ---- stream attn out NOW (overlaps PV below): 2 rows/wave, 1KB lines ----
  #pragma unroll
  for (int rg = 0; rg < 2; rg++) {
    int row = w * 2 + rg;
    float* arow = attn + ((size_t)bh * 1024 + r0 + row) * 1024;
    int swr = row & 7;
    #pragma unroll
    for (int it = 0; it < 4; it++) {
      int ci = it * 64 + l;              // 16B output chunk (4 f32)
      uint2 d = *(const uint2*)((const char*)P + row * 2048 +
                                (((ci >> 1) ^ swr) << 4) + ((ci & 1) << 3));
      float4 o;
      o.x = __uint_as_float(d.x << 16);
      o.y = __uint_as_float(d.x & 0xffff0000u);
      o.z = __uint_as_float(d.y << 16);
      o.w = __uint_as_float(d.y & 0xffff0000u);
      *(float4*)&arow[ci * 4] = o;
    }
  }

  // ---- phase 3: ctx = P @ V; wave w: dim-grp dg=w&3, col-half ch=w>>2 ----
  const int dg = w & 3, ch = w >> 2;
  f32x4 o0 = {}, o1 = {};
  #pragma unroll
  for (int j = 0; j < 16; j++) {
    int jj = ch * 16 + j;
    const short* vfp = vf_ + (((size_t)(bh * 4 + dg) * 32 + jj) << 9);
    bfx8 bv = *(const bfx8*)&vfp[l * 8];
    int slot_lin = jj * 4 + lk;
    bfx8 pa = *(const bfx8*)((const char*)P + lr * 2048 +
                             ((slot_lin ^ (lr & 7)) << 4));
    if (j & 1) o1 = __builtin_amdgcn_mfma_f32_16x16x32_bf16(pa, bv, o1, 0, 0, 0);
    else       o0 = __builtin_amdgcn_mfma_f32_16x16x32_bf16(pa, bv, o0, 0, 0, 0);
  }

  // ---- cross-wave (col-half) reduce + ctx store ----
  f32x4 oo;
  #pragma unroll
  for (int i = 0; i < 4; i++) oo[i] = o0[i] + o1[i];
  if (w >= 4) redC[(w - 4) * 64 + l] = oo;
  __syncthreads();
  if (w < 4) {
    f32x4 op = redC[w * 64 + l];
    #pragma unroll
    for (int i = 0; i < 4; i++) {
      float v = oo[i] + op[i];
      ctx[(((size_t)b << 10) + r0 + 4 * lk + i) * 1024 + (h << 6) + (w << 4) + lr] =
          f2bfbits(v);
    }
  }
}

// ---------------- launch ----------------

extern "C" void kernel_launch(void* const* d_in, const int* in_sizes, int n_in,
                              void* d_out, int out_size, void* d_ws, size_t ws_size,
                              hipStream_t stream) {
  const float* x    = (const float*)d_in[0];
  const int*   mask = (const int*)d_in[1];
  const float* Wqkv = (const float*)d_in[2];
  const float* bqkv = (const float*)d_in[3];
  const float* Wout = (const float*)d_in[4];
  const float* bout = (const float*)d_in[5];
  float* out  = (float*)d_out;
  float* attn = out + (size_t)4 * 1024 * 1024;

  char* ws = (char*)d_ws;
  short* xb    = (short*)(ws);                  //  8 MB  x bf16 [4096][1024]
  short* wqkvT = (short*)(ws + 8388608);        //  6 MB  [3072][1024]
  short* woutT = (short*)(ws + 14680064);       //  2 MB  [1024][1024]
  short* qfr   = (short*)(ws + 16777216);       //  8 MB  Q fragments
  short* kfr   = (short*)(ws + 25165824);       //  8 MB  K fragments
  short* vfr   = (short*)(ws + 33554432);       //  8 MB  V fragments
  short* ctx   = (short*)(ws + 41943040);       //  8 MB  [4096][1024]
  unsigned char* msk = (unsigned char*)(ws + 50331648);  // 4 KB

  k_prep<<<4112, 256, 0, stream>>>(x, xb, mask, msk);
  k_transpose2<<<dim3(128, 32), dim3(32, 8), 0, stream>>>(Wqkv, wqkvT, Wout, woutT);
  k_gemm<<<dim3(24, 32), 256, 0, stream>>>(xb, wqkvT, bqkv, 1024, qfr, kfr, vfr);
  k_attn<<<4096, 512, 0, stream>>>(qfr, kfr, vfr, msk, attn, ctx);
  k_gemm_out<<<dim3(16, 32), 256, 0, stream>>>(ctx, woutT, bout, out);
}

// Round 7
// 144.509 us; speedup vs baseline: 1.6252x; 1.0321x over previous
//
#include <hip/hip_runtime.h>
#include <stdint.h>

#define DEV static __device__ __forceinline__

typedef __attribute__((ext_vector_type(8))) __bf16 bfx8;
typedef __attribute__((ext_vector_type(4))) float f32x4;

DEV short f2bfbits(float f) {
  union { float f; unsigned u; } v; v.f = f;
  unsigned r = v.u + 0x7fffu + ((v.u >> 16) & 1u);
  return (short)(r >> 16);
}

DEV void gload_lds16(const void* g, void* lds) {
  __builtin_amdgcn_global_load_lds(
      (const __attribute__((address_space(1))) void*)g,
      (__attribute__((address_space(3))) void*)lds, 16, 0, 0);
}

// ---------------- prep (merged): x->bf16 | mask | both weight transposes ----------------
__global__ void k_prep(const float* __restrict__ x, short* __restrict__ xb,
                       const int* __restrict__ mask, unsigned char* __restrict__ msk,
                       const float* __restrict__ Wqkv, short* __restrict__ wqkvT,
                       const float* __restrict__ Wout, short* __restrict__ woutT) {
  __shared__ float tile[32][33];
  int bx = blockIdx.x;
  int t = threadIdx.x;
  if (bx < 4096) {
    int i = bx * 256 + t;                            // 4 floats per thread
    float4 v = ((const float4*)x)[i];
    union { short s[4]; uint64_t u; } o;
    o.s[0] = f2bfbits(v.x); o.s[1] = f2bfbits(v.y);
    o.s[2] = f2bfbits(v.z); o.s[3] = f2bfbits(v.w);
    ((uint64_t*)xb)[i] = o.u;
  } else if (bx < 4112) {
    int i = (bx - 4096) * 256 + t;                   // [0, 4096)
    int b = i >> 10, n = i & 1023;
    msk[i] = (n == 0) ? (unsigned char)1 : (unsigned char)(mask[b * 1023 + n - 1] != 0);
  } else {
    int tb = bx - 4112;                              // 4096 transpose blocks
    int bxx = tb & 127, byy = tb >> 7;
    const float* src; short* dst; int C;
    if (bxx < 96) { src = Wqkv; dst = wqkvT; C = 3072; }
    else          { src = Wout; dst = woutT; C = 1024; bxx -= 96; }
    const int R = 1024;
    int c0 = bxx * 32, r0 = byy * 32;
    int tx = t & 31, ty = t >> 5;                    // (32,8)
    #pragma unroll
    for (int j = 0; j < 32; j += 8)
      tile[ty + j][tx] = src[(size_t)(r0 + ty + j) * C + c0 + tx];
    __syncthreads();
    #pragma unroll
    for (int j = 0; j < 32; j += 8)
      dst[(size_t)(c0 + ty + j) * R + r0 + tx] = f2bfbits(tile[tx][ty + j]);
  }
}

// ---------------- QKV GEMM: C = A[M][K] @ Bt[N][K]^T + bias -> fragment layouts ----
//   q/kfrag: [bh][blk=n>>4][half=d>>5][lane=((d>>3)&3)*16+(n&15)][8]   (2KB per blk)
//   vfrag:   [bh][db=d>>4][jj=n>>5][lane=((n>>3)&3)*16+(d&15)][8]      (1KB per jj)
// Epilogue: 2 passes; acc -> 16KB LDS image in fragment order -> coalesced 16B stores.
__global__ __launch_bounds__(256)
void k_gemm(const short* __restrict__ A, const short* __restrict__ Bt,
            const float* __restrict__ bias, int K,
            short* __restrict__ qf, short* __restrict__ kf,
            short* __restrict__ vf) {
  __shared__ short smem[8192];        // 16KB: staging As|Bs, then epilogue image
  short* As = smem;
  short* Bs = smem + 4096;
  const int t = threadIdx.x;
  const int l = t & 63, w = t >> 6;
  const int lr = l & 15, lk = l >> 4;
  const int m0 = blockIdx.y * 128, n0 = blockIdx.x * 128;
  const int wr = (w >> 1) * 64, wc = (w & 1) * 64;
  f32x4 acc[4][4] = {};

  const int srow = t >> 2;
  const int sc8 = (t & 3) * 8;
  const size_t aoff1 = (size_t)(m0 + srow) * K + sc8;
  const size_t aoff2 = (size_t)(m0 + srow + 64) * K + sc8;
  const size_t boff1 = (size_t)(n0 + srow) * K + sc8;
  const size_t boff2 = (size_t)(n0 + srow + 64) * K + sc8;
  short* asd1 = As + (t & ~63) * 8;
  short* asd2 = As + (t & ~63) * 8 + 2048;
  short* bsd1 = Bs + (t & ~63) * 8;
  short* bsd2 = Bs + (t & ~63) * 8 + 2048;

  for (int k0 = 0; k0 < K; k0 += 32) {
    gload_lds16(A + aoff1 + k0, asd1);
    gload_lds16(A + aoff2 + k0, asd2);
    gload_lds16(Bt + boff1 + k0, bsd1);
    gload_lds16(Bt + boff2 + k0, bsd2);
    __syncthreads();
    bfx8 af[4], bf[4];
    #pragma unroll
    for (int m = 0; m < 4; m++)
      af[m] = *(const bfx8*)&As[(wr + m * 16 + lr) * 32 + lk * 8];
    #pragma unroll
    for (int n = 0; n < 4; n++)
      bf[n] = *(const bfx8*)&Bs[(wc + n * 16 + lr) * 32 + lk * 8];
    #pragma unroll
    for (int m = 0; m < 4; m++)
      #pragma unroll
      for (int n = 0; n < 4; n++)
        acc[m][n] = __builtin_amdgcn_mfma_f32_16x16x32_bf16(af[m], bf[n], acc[m][n], 0, 0, 0);
    __syncthreads();
  }

  // ---- epilogue: fragment-ordered LDS image, then coalesced stores ----
  const int which = n0 >> 10;                 // 0=q 1=k 2=v (tiles never straddle)
  const int head = w & 1;                     // head within the 128-col tile
  const int band = w >> 1;                    // row band (wr/64)
  const int bb = m0 >> 10;
  const int bh = bb * 16 + ((n0 & 1023) >> 6) + head;
  short* dstp = (which == 0) ? qf : (which == 1) ? kf : vf;

  #pragma unroll
  for (int p = 0; p < 2; p++) {
    // write this pass's acc (m = 2p, 2p+1) into the 16KB LDS image
    #pragma unroll
    for (int mm = 0; mm < 2; mm++) {
      int m = 2 * p + mm;
      #pragma unroll
      for (int n = 0; n < 4; n++) {
        int gc = n0 + wc + n * 16 + lr;
        float bv = bias[gc];
        #pragma unroll
        for (int i = 0; i < 4; i++) {
          short val = f2bfbits(acc[m][n][i] + bv);
          int off;
          if (which < 2) {
            // [band][head][blk=mm][half=n>>1][lane=((2n+(lr>>3))&3)*16+4lk+i][8]+(lr&7)
            off = ((((band * 2 + head) * 2 + mm) * 2 + (n >> 1)) * 64 +
                   ((2 * n + (lr >> 3)) & 3) * 16 + 4 * lk + i) * 8 + (lr & 7);
          } else {
            // [band][head][db=n][lane=(2mm+((4lk+i)>>3))*16+lr][8]+((4lk+i)&7)
            off = (((band * 2 + head) * 4 + n) * 64 +
                   (2 * mm + ((4 * lk + i) >> 3)) * 16 + lr) * 8 + ((4 * lk + i) & 7);
          }
          smem[off] = val;
        }
      }
    }
    __syncthreads();
    // dump 4 regions of 4KB, fully coalesced (16B/thread/region)
    if (which < 2) {
      #pragma unroll
      for (int r = 0; r < 4; r++) {
        int rb = r >> 1, rh = r & 1;
        int bh_r = bb * 16 + ((n0 & 1023) >> 6) + rh;
        int blk0 = ((m0 & 1023) >> 4) + 4 * rb + 2 * p;
        size_t g = ((size_t)(bh_r * 64 + blk0) << 10) + t * 8;
        *(int4*)&dstp[g] = *(const int4*)&smem[r * 2048 + t * 8];
      }
    } else {
      #pragma unroll
      for (int r = 0; r < 4; r++) {
        int rb = r >> 1, rh = r & 1;
        int bh_r = bb * 16 + ((n0 & 1023) >> 6) + rh;
        int jj = ((m0 & 1023) >> 5) + 2 * rb + p;
        int db = t >> 6;
        size_t g = (((size_t)(bh_r * 4 + db) * 32 + jj) << 9) + (t & 63) * 8;
        *(int4*)&dstp[g] = *(const int4*)&smem[r * 2048 + t * 8];
      }
    }
    if (p == 0) __syncthreads();
  }
}

// ---------------- out GEMM: BM=128, BN=64 -> 512 WGs (2/CU) ----------------
__global__ __launch_bounds__(256)
void k_gemm_out(const short* __restrict__ A, const short* __restrict__ Bt,
                const float* __restrict__ bias, float* __restrict__ outF) {
  __shared__ short As[128 * 32];
  __shared__ short Bs[64 * 32];
  const int K = 1024;
  const int t = threadIdx.x;
  const int l = t & 63, w = t >> 6;
  const int lr = l & 15, lk = l >> 4;
  const int m0 = blockIdx.y * 128, n0 = blockIdx.x * 64;
  const int wr = (w >> 1) * 64, wc = (w & 1) * 32;
  f32x4 acc[4][2] = {};

  const int srow = t >> 2;
  const int sc8 = (t & 3) * 8;
  const size_t aoff1 = (size_t)(m0 + srow) * K + sc8;
  const size_t aoff2 = (size_t)(m0 + srow + 64) * K + sc8;
  const size_t boff1 = (size_t)(n0 + srow) * K + sc8;
  short* asd1 = As + (t & ~63) * 8;
  short* asd2 = As + (t & ~63) * 8 + 2048;
  short* bsd1 = Bs + (t & ~63) * 8;

  for (int k0 = 0; k0 < K; k0 += 32) {
    gload_lds16(A + aoff1 + k0, asd1);
    gload_lds16(A + aoff2 + k0, asd2);
    gload_lds16(Bt + boff1 + k0, bsd1);
    __syncthreads();
    bfx8 af[4], bf[2];
    #pragma unroll
    for (int m = 0; m < 4; m++)
      af[m] = *(const bfx8*)&As[(wr + m * 16 + lr) * 32 + lk * 8];
    #pragma unroll
    for (int n = 0; n < 2; n++)
      bf[n] = *(const bfx8*)&Bs[(wc + n * 16 + lr) * 32 + lk * 8];
    #pragma unroll
    for (int m = 0; m < 4; m++)
      #pragma unroll
      for (int n = 0; n < 2; n++)
        acc[m][n] = __builtin_amdgcn_mfma_f32_16x16x32_bf16(af[m], bf[n], acc[m][n], 0, 0, 0);
    __syncthreads();
  }

  #pragma unroll
  for (int m = 0; m < 4; m++) {
    #pragma unroll
    for (int n = 0; n < 2; n++) {
      int gc = n0 + wc + n * 16 + lr;
      float bv = bias[gc];
      #pragma unroll
      for (int i = 0; i < 4; i++) {
        int gr = m0 + wr + m * 16 + 4 * lk + i;
        outF[(size_t)gr * 1024 + gc] = acc[m][n][i] + bv;
      }
    }
  }
}

// ---------------- fused attention v5 (unchanged) ----------------
__global__ __launch_bounds__(512, 4)
void k_attn(const short* __restrict__ qf_, const short* __restrict__ kf_,
            const short* __restrict__ vf_, const unsigned char* __restrict__ msk,
            float* __restrict__ attn, short* __restrict__ ctx) {
  __shared__ short P[16 * 1024];      // 32KB bf16 P, swizzled 16B slots
  __shared__ float redM[16][8];
  __shared__ float redS[16][8];
  __shared__ f32x4 redC[256];         // 4KB ctx cross-wave reduce
  const int t = threadIdx.x, l = t & 63, w = t >> 6;
  const int lr = l & 15, lk = l >> 4;
  // XCD-chunked swizzle: 4096 WGs = 8 XCDs x 512; 64 consecutive = one (b,h)
  const int wg = ((blockIdx.x & 7) << 9) | (blockIdx.x >> 3);
  const int rt = wg & 63, h = (wg >> 6) & 15, b = wg >> 10;
  const int bh = b * 16 + h;
  const int r0 = rt * 16;
  const float NEG = -3.402823466e38f;

  // Q fragment: lane l -> q row r0+lr, k-octet lk (+half*32)
  const short* qf = qf_ + ((size_t)(bh * 64 + rt) << 10);
  bfx8 aq0 = *(const bfx8*)&qf[l * 8];
  bfx8 aq1 = *(const bfx8*)&qf[512 + l * 8];

  const unsigned char* mb = msk + b * 1024;
  const bool rowok = mb[r0 + lr] != 0;

  // ---- phase 1: QK^T, wave w owns cols w*128..w*128+127 ----
  f32x4 sc[8];
  #pragma unroll
  for (int cc = 0; cc < 8; cc++) {
    const short* kfp = kf_ + ((size_t)(bh * 64 + w * 8 + cc) << 10);
    bfx8 bk0 = *(const bfx8*)&kfp[l * 8];
    bfx8 bk1 = *(const bfx8*)&kfp[512 + l * 8];
    f32x4 a = {};
    a = __builtin_amdgcn_mfma_f32_16x16x32_bf16(bk0, aq0, a, 0, 0, 0);
    a = __builtin_amdgcn_mfma_f32_16x16x32_bf16(bk1, aq1, a, 0, 0, 0);
    unsigned cm = *(const unsigned*)&mb[w * 128 + cc * 16 + 4 * lk];
    #pragma unroll
    for (int i = 0; i < 4; i++) {
      bool ok = rowok && (((cm >> (8 * i)) & 0xffu) != 0u);
      sc[cc][i] = ok ? a[i] * 0.03125f : NEG;
    }
  }

  // ---- phase 2: softmax over k (row = lr) ----
  float m = NEG;
  #pragma unroll
  for (int f = 0; f < 8; f++)
    #pragma unroll
    for (int i = 0; i < 4; i++) m = fmaxf(m, sc[f][i]);
  m = fmaxf(m, __shfl_xor(m, 16));
  m = fmaxf(m, __shfl_xor(m, 32));
  if (lk == 0) redM[lr][w] = m;
  __syncthreads();
  {
    float4 m0 = *(const float4*)&redM[lr][0];
    float4 m1 = *(const float4*)&redM[lr][4];
    m = fmaxf(fmaxf(fmaxf(m0.x, m0.y), fmaxf(m0.z, m0.w)),
              fmaxf(fmaxf(m1.x, m1.y), fmaxf(m1.z, m1.w)));
  }
  float s = 0.f;
  #pragma unroll
  for (int f = 0; f < 8; f++)
    #pragma unroll
    for (int i = 0; i < 4; i++) { sc[f][i] = __expf(sc[f][i] - m); s += sc[f][i]; }
  s += __shfl_xor(s, 16);
  s += __shfl_xor(s, 32);
  if (lk == 0) redS[lr][w] = s;
  __syncthreads();
  float inv;
  {
    float4 s0 = *(const float4*)&redS[lr][0];
    float4 s1 = *(const float4*)&redS[lr][4];
    inv = 1.0f / (s0.x + s0.y + s0.z + s0.w + s1.x + s1.y + s1.z + s1.w);
  }

  // ---- P (bf16) -> LDS, swizzled: row lr, col w*128 + cc*16 + 4lk ----
  #pragma unroll
  for (int cc = 0; cc < 8; cc++) {
    union { ushort u[4]; uint2 d; } pk;
    pk.u[0] = (ushort)f2bfbits(sc[cc][0] * inv);
    pk.u[1] = (ushort)f2bfbits(sc[cc][1] * inv);
    pk.u[2] = (ushort)f2bfbits(sc[cc][2] * inv);
    pk.u[3] = (ushort)f2bfbits(sc[cc][3] * inv);
    int slot_lin = w * 16 + cc * 2 + (lk >> 1);
    int addr = lr * 2048 + ((slot_lin ^ (lr & 7)) << 4) + ((lk & 1) << 3);
    *(uint2*)((char*)P + addr) = pk.d;
  }
  __syncthreads();   // P visible to all waves

  // ---- stream attn out NOW (overlaps PV below): 2 rows/wave, 1KB lines ----
  #pragma unroll
  for (int rg = 0; rg < 2; rg++) {
    int row = w * 2 + rg;
    float* arow = attn + ((size_t)bh * 1024 + r0 + row) * 1024;
    int swr = row & 7;
    #pragma unroll
    for (int it = 0; it < 4; it++) {
      int ci = it * 64 + l;              // 16B output chunk (4 f32)
      uint2 d = *(const uint2*)((const char*)P + row * 2048 +
                                (((ci >> 1) ^ swr) << 4) + ((ci & 1) << 3));
      float4 o;
      o.x = __uint_as_float(d.x << 16);
      o.y = __uint_as_float(d.x & 0xffff0000u);
      o.z = __uint_as_float(d.y << 16);
      o.w = __uint_as_float(d.y & 0xffff0000u);
      *(float4*)&arow[ci * 4] = o;
    }
  }

  // ---- phase 3: ctx = P @ V; wave w: dim-grp dg=w&3, col-half ch=w>>2 ----
  const int dg = w & 3, ch = w >> 2;
  f32x4 o0 = {}, o1 = {};
  #pragma unroll
  for (int j = 0; j < 16; j++) {
    int jj = ch * 16 + j;
    const short* vfp = vf_ + (((size_t)(bh * 4 + dg) * 32 + jj) << 9);
    bfx8 bv = *(const bfx8*)&vfp[l * 8];
    int slot_lin = jj * 4 + lk;
    bfx8 pa = *(const bfx8*)((const char*)P + lr * 2048 +
                             ((slot_lin ^ (lr & 7)) << 4));
    if (j & 1) o1 = __builtin_amdgcn_mfma_f32_16x16x32_bf16(pa, bv, o1, 0, 0, 0);
    else       o0 = __builtin_amdgcn_mfma_f32_16x16x32_bf16(pa, bv, o0, 0, 0, 0);
  }

  // ---- cross-wave (col-half) reduce + ctx store ----
  f32x4 oo;
  #pragma unroll
  for (int i = 0; i < 4; i++) oo[i] = o0[i] + o1[i];
  if (w >= 4) redC[(w - 4) * 64 + l] = oo;
  __syncthreads();
  if (w < 4) {
    f32x4 op = redC[w * 64 + l];
    #pragma unroll
    for (int i = 0; i < 4; i++) {
      float v = oo[i] + op[i];
      ctx[(((size_t)b << 10) + r0 + 4 * lk + i) * 1024 + (h << 6) + (w << 4) + lr] =
          f2bfbits(v);
    }
  }
}

// ---------------- launch ----------------

extern "C" void kernel_launch(void* const* d_in, const int* in_sizes, int n_in,
                              void* d_out, int out_size, void* d_ws, size_t ws_size,
                              hipStream_t stream) {
  const float* x    = (const float*)d_in[0];
  const int*   mask = (const int*)d_in[1];
  const float* Wqkv = (const float*)d_in[2];
  const float* bqkv = (const float*)d_in[3];
  const float* Wout = (const float*)d_in[4];
  const float* bout = (const float*)d_in[5];
  float* out  = (float*)d_out;
  float* attn = out + (size_t)4 * 1024 * 1024;

  char* ws = (char*)d_ws;
  short* xb    = (short*)(ws);                  //  8 MB  x bf16 [4096][1024]
  short* wqkvT = (short*)(ws + 8388608);        //  6 MB  [3072][1024]
  short* woutT = (short*)(ws + 14680064);       //  2 MB  [1024][1024]
  short* qfr   = (short*)(ws + 16777216);       //  8 MB  Q fragments
  short* kfr   = (short*)(ws + 25165824);       //  8 MB  K fragments
  short* vfr   = (short*)(ws + 33554432);       //  8 MB  V fragments
  short* ctx   = (short*)(ws + 41943040);       //  8 MB  [4096][1024]
  unsigned char* msk = (unsigned char*)(ws + 50331648);  // 4 KB

  k_prep<<<8208, 256, 0, stream>>>(x, xb, mask, msk, Wqkv, wqkvT, Wout, woutT);
  k_gemm<<<dim3(24, 32), 256, 0, stream>>>(xb, wqkvT, bqkv, 1024, qfr, kfr, vfr);
  k_attn<<<4096, 512, 0, stream>>>(qfr, kfr, vfr, msk, attn, ctx);
  k_gemm_out<<<dim3(16, 32), 256, 0, stream>>>(ctx, woutT, bout, out);
}

// Round 8
// 141.953 us; speedup vs baseline: 1.6545x; 1.0180x over previous
//
#include <hip/hip_runtime.h>
#include <stdint.h>

#define DEV static __device__ __forceinline__

typedef __attribute__((ext_vector_type(8))) __bf16 bfx8;
typedef __attribute__((ext_vector_type(4))) float f32x4;

DEV short f2bfbits(float f) {
  union { float f; unsigned u; } v; v.f = f;
  unsigned r = v.u + 0x7fffu + ((v.u >> 16) & 1u);
  return (short)(r >> 16);
}

DEV void gload_lds16(const void* g, void* lds) {
  __builtin_amdgcn_global_load_lds(
      (const __attribute__((address_space(1))) void*)g,
      (__attribute__((address_space(3))) void*)lds, 16, 0, 0);
}

// ---------------- prep (merged): x->bf16 | mask | both weight transposes ----------------
__global__ void k_prep(const float* __restrict__ x, short* __restrict__ xb,
                       const int* __restrict__ mask, unsigned char* __restrict__ msk,
                       const float* __restrict__ Wqkv, short* __restrict__ wqkvT,
                       const float* __restrict__ Wout, short* __restrict__ woutT) {
  __shared__ float tile[32][33];
  int bx = blockIdx.x;
  int t = threadIdx.x;
  if (bx < 4096) {
    int i = bx * 256 + t;                            // 4 floats per thread
    float4 v = ((const float4*)x)[i];
    union { short s[4]; uint64_t u; } o;
    o.s[0] = f2bfbits(v.x); o.s[1] = f2bfbits(v.y);
    o.s[2] = f2bfbits(v.z); o.s[3] = f2bfbits(v.w);
    ((uint64_t*)xb)[i] = o.u;
  } else if (bx < 4112) {
    int i = (bx - 4096) * 256 + t;                   // [0, 4096)
    int b = i >> 10, n = i & 1023;
    msk[i] = (n == 0) ? (unsigned char)1 : (unsigned char)(mask[b * 1023 + n - 1] != 0);
  } else {
    int tb = bx - 4112;                              // 4096 transpose blocks
    int bxx = tb & 127, byy = tb >> 7;
    const float* src; short* dst; int C;
    if (bxx < 96) { src = Wqkv; dst = wqkvT; C = 3072; }
    else          { src = Wout; dst = woutT; C = 1024; bxx -= 96; }
    const int R = 1024;
    int c0 = bxx * 32, r0 = byy * 32;
    int tx = t & 31, ty = t >> 5;                    // (32,8)
    #pragma unroll
    for (int j = 0; j < 32; j += 8)
      tile[ty + j][tx] = src[(size_t)(r0 + ty + j) * C + c0 + tx];
    __syncthreads();
    #pragma unroll
    for (int j = 0; j < 32; j += 8)
      dst[(size_t)(c0 + ty + j) * R + r0 + tx] = f2bfbits(tile[tx][ty + j]);
  }
}

// ---------------- QKV GEMM: C = A[M][K] @ Bt[N][K]^T + bias -> fragment layouts ----
//   q/kfrag: [bh][blk=n>>4][half=d>>5][lane=((d>>3)&3)*16+(n&15)][8]   (2KB per blk)
//   vfrag:   [bh][db=d>>4][jj=n>>5][lane=((n>>3)&3)*16+(d&15)][8]      (1KB per jj)
__global__ __launch_bounds__(256)
void k_gemm(const short* __restrict__ A, const short* __restrict__ Bt,
            const float* __restrict__ bias, int K,
            short* __restrict__ qf, short* __restrict__ kf,
            short* __restrict__ vf) {
  __shared__ short smem[8192];        // 16KB: staging As|Bs, then epilogue image
  short* As = smem;
  short* Bs = smem + 4096;
  const int t = threadIdx.x;
  const int l = t & 63, w = t >> 6;
  const int lr = l & 15, lk = l >> 4;
  const int m0 = blockIdx.y * 128, n0 = blockIdx.x * 128;
  const int wr = (w >> 1) * 64, wc = (w & 1) * 64;
  f32x4 acc[4][4] = {};

  const int srow = t >> 2;
  const int sc8 = (t & 3) * 8;
  const size_t aoff1 = (size_t)(m0 + srow) * K + sc8;
  const size_t aoff2 = (size_t)(m0 + srow + 64) * K + sc8;
  const size_t boff1 = (size_t)(n0 + srow) * K + sc8;
  const size_t boff2 = (size_t)(n0 + srow + 64) * K + sc8;
  short* asd1 = As + (t & ~63) * 8;
  short* asd2 = As + (t & ~63) * 8 + 2048;
  short* bsd1 = Bs + (t & ~63) * 8;
  short* bsd2 = Bs + (t & ~63) * 8 + 2048;

  for (int k0 = 0; k0 < K; k0 += 32) {
    gload_lds16(A + aoff1 + k0, asd1);
    gload_lds16(A + aoff2 + k0, asd2);
    gload_lds16(Bt + boff1 + k0, bsd1);
    gload_lds16(Bt + boff2 + k0, bsd2);
    __syncthreads();
    bfx8 af[4], bf[4];
    #pragma unroll
    for (int m = 0; m < 4; m++)
      af[m] = *(const bfx8*)&As[(wr + m * 16 + lr) * 32 + lk * 8];
    #pragma unroll
    for (int n = 0; n < 4; n++)
      bf[n] = *(const bfx8*)&Bs[(wc + n * 16 + lr) * 32 + lk * 8];
    #pragma unroll
    for (int m = 0; m < 4; m++)
      #pragma unroll
      for (int n = 0; n < 4; n++)
        acc[m][n] = __builtin_amdgcn_mfma_f32_16x16x32_bf16(af[m], bf[n], acc[m][n], 0, 0, 0);
    __syncthreads();
  }

  // ---- epilogue: fragment-ordered LDS image, then coalesced stores ----
  const int which = n0 >> 10;                 // 0=q 1=k 2=v (tiles never straddle)
  const int head = w & 1;                     // head within the 128-col tile
  const int band = w >> 1;                    // row band (wr/64)
  const int bb = m0 >> 10;
  short* dstp = (which == 0) ? qf : (which == 1) ? kf : vf;

  #pragma unroll
  for (int p = 0; p < 2; p++) {
    #pragma unroll
    for (int mm = 0; mm < 2; mm++) {
      int m = 2 * p + mm;
      #pragma unroll
      for (int n = 0; n < 4; n++) {
        int gc = n0 + wc + n * 16 + lr;
        float bv = bias[gc];
        #pragma unroll
        for (int i = 0; i < 4; i++) {
          short val = f2bfbits(acc[m][n][i] + bv);
          int off;
          if (which < 2) {
            off = ((((band * 2 + head) * 2 + mm) * 2 + (n >> 1)) * 64 +
                   ((2 * n + (lr >> 3)) & 3) * 16 + 4 * lk + i) * 8 + (lr & 7);
          } else {
            off = (((band * 2 + head) * 4 + n) * 64 +
                   (2 * mm + ((4 * lk + i) >> 3)) * 16 + lr) * 8 + ((4 * lk + i) & 7);
          }
          smem[off] = val;
        }
      }
    }
    __syncthreads();
    if (which < 2) {
      #pragma unroll
      for (int r = 0; r < 4; r++) {
        int rb = r >> 1, rh = r & 1;
        int bh_r = bb * 16 + ((n0 & 1023) >> 6) + rh;
        int blk0 = ((m0 & 1023) >> 4) + 4 * rb + 2 * p;
        size_t g = ((size_t)(bh_r * 64 + blk0) << 10) + t * 8;
        *(int4*)&dstp[g] = *(const int4*)&smem[r * 2048 + t * 8];
      }
    } else {
      #pragma unroll
      for (int r = 0; r < 4; r++) {
        int rb = r >> 1, rh = r & 1;
        int bh_r = bb * 16 + ((n0 & 1023) >> 6) + rh;
        int jj = ((m0 & 1023) >> 5) + 2 * rb + p;
        int db = t >> 6;
        size_t g = (((size_t)(bh_r * 4 + db) * 32 + jj) << 9) + (t & 63) * 8;
        *(int4*)&dstp[g] = *(const int4*)&smem[r * 2048 + t * 8];
      }
    }
    if (p == 0) __syncthreads();
  }
}

// ---------------- out GEMM: BM=128, BN=64 -> 512 WGs (2/CU) ----------------
__global__ __launch_bounds__(256)
void k_gemm_out(const short* __restrict__ A, const short* __restrict__ Bt,
                const float* __restrict__ bias, float* __restrict__ outF) {
  __shared__ short As[128 * 32];
  __shared__ short Bs[64 * 32];
  const int K = 1024;
  const int t = threadIdx.x;
  const int l = t & 63, w = t >> 6;
  const int lr = l & 15, lk = l >> 4;
  const int m0 = blockIdx.y * 128, n0 = blockIdx.x * 64;
  const int wr = (w >> 1) * 64, wc = (w & 1) * 32;
  f32x4 acc[4][2] = {};

  const int srow = t >> 2;
  const int sc8 = (t & 3) * 8;
  const size_t aoff1 = (size_t)(m0 + srow) * K + sc8;
  const size_t aoff2 = (size_t)(m0 + srow + 64) * K + sc8;
  const size_t boff1 = (size_t)(n0 + srow) * K + sc8;
  short* asd1 = As + (t & ~63) * 8;
  short* asd2 = As + (t & ~63) * 8 + 2048;
  short* bsd1 = Bs + (t & ~63) * 8;

  for (int k0 = 0; k0 < K; k0 += 32) {
    gload_lds16(A + aoff1 + k0, asd1);
    gload_lds16(A + aoff2 + k0, asd2);
    gload_lds16(Bt + boff1 + k0, bsd1);
    __syncthreads();
    bfx8 af[4], bf[2];
    #pragma unroll
    for (int m = 0; m < 4; m++)
      af[m] = *(const bfx8*)&As[(wr + m * 16 + lr) * 32 + lk * 8];
    #pragma unroll
    for (int n = 0; n < 2; n++)
      bf[n] = *(const bfx8*)&Bs[(wc + n * 16 + lr) * 32 + lk * 8];
    #pragma unroll
    for (int m = 0; m < 4; m++)
      #pragma unroll
      for (int n = 0; n < 2; n++)
        acc[m][n] = __builtin_amdgcn_mfma_f32_16x16x32_bf16(af[m], bf[n], acc[m][n], 0, 0, 0);
    __syncthreads();
  }

  #pragma unroll
  for (int m = 0; m < 4; m++) {
    #pragma unroll
    for (int n = 0; n < 2; n++) {
      int gc = n0 + wc + n * 16 + lr;
      float bv = bias[gc];
      #pragma unroll
      for (int i = 0; i < 4; i++) {
        int gr = m0 + wr + m * 16 + 4 * lk + i;
        outF[(size_t)gr * 1024 + gc] = acc[m][n][i] + bv;
      }
    }
  }
}

// ---------------- fused attention v6: QBLK=32, 2048 WGs ----------------
// WG = (b,h) x 32 q-rows, 8 waves. Direct fragment loads (no staging).
// QK^T: wave w owns cols w*128..+127 for all 32 rows (sc[2][8]).
// PV: wave w owns (row-block rb=w>>2, dim-grp dg=w&3) -> complete rows, NO
// cross-wave reduce. P bf16 64KB LDS. 2 WG/CU (LDS-limited).
__global__ __launch_bounds__(512, 2)
void k_attn(const short* __restrict__ qf_, const short* __restrict__ kf_,
            const short* __restrict__ vf_, const unsigned char* __restrict__ msk,
            float* __restrict__ attn, short* __restrict__ ctx) {
  __shared__ short P[32 * 1024];      // 64KB bf16 P, swizzled 16B slots
  __shared__ float redM[32][8];
  __shared__ float redS[32][8];
  const int t = threadIdx.x, l = t & 63, w = t >> 6;
  const int lr = l & 15, lk = l >> 4;
  // XCD-chunked swizzle: 2048 WGs = 8 XCDs x 256; 32 consecutive = one (b,h)
  const int wg = ((blockIdx.x & 7) << 8) | (blockIdx.x >> 3);
  const int rt = wg & 31, h = (wg >> 5) & 15, b = wg >> 9;
  const int bh = b * 16 + h;
  const int r0 = rt * 32;
  const float NEG = -3.402823466e38f;

  // Q fragments: blocks rt*2, rt*2+1 (rows r0..r0+31)
  const short* qf = qf_ + ((size_t)(bh * 64 + rt * 2) << 10);
  bfx8 aq00 = *(const bfx8*)&qf[l * 8];
  bfx8 aq01 = *(const bfx8*)&qf[512 + l * 8];
  bfx8 aq10 = *(const bfx8*)&qf[1024 + l * 8];
  bfx8 aq11 = *(const bfx8*)&qf[1536 + l * 8];

  const unsigned char* mb = msk + b * 1024;
  const bool rowok0 = mb[r0 + lr] != 0;
  const bool rowok1 = mb[r0 + 16 + lr] != 0;

  // ---- phase 1: QK^T, sc[qb][cc] ----
  f32x4 sc[2][8];
  #pragma unroll
  for (int cc = 0; cc < 8; cc++) {
    const short* kfp = kf_ + ((size_t)(bh * 64 + w * 8 + cc) << 10);
    bfx8 bk0 = *(const bfx8*)&kfp[l * 8];
    bfx8 bk1 = *(const bfx8*)&kfp[512 + l * 8];
    f32x4 a0 = {}, a1 = {};
    a0 = __builtin_amdgcn_mfma_f32_16x16x32_bf16(bk0, aq00, a0, 0, 0, 0);
    a0 = __builtin_amdgcn_mfma_f32_16x16x32_bf16(bk1, aq01, a0, 0, 0, 0);
    a1 = __builtin_amdgcn_mfma_f32_16x16x32_bf16(bk0, aq10, a1, 0, 0, 0);
    a1 = __builtin_amdgcn_mfma_f32_16x16x32_bf16(bk1, aq11, a1, 0, 0, 0);
    unsigned cm = *(const unsigned*)&mb[w * 128 + cc * 16 + 4 * lk];
    #pragma unroll
    for (int i = 0; i < 4; i++) {
      bool cok = ((cm >> (8 * i)) & 0xffu) != 0u;
      sc[0][cc][i] = (cok && rowok0) ? a0[i] * 0.03125f : NEG;
      sc[1][cc][i] = (cok && rowok1) ? a1[i] * 0.03125f : NEG;
    }
  }

  // ---- phase 2: softmax per row (rows qb*16+lr) ----
  float m0r = NEG, m1r = NEG;
  #pragma unroll
  for (int f = 0; f < 8; f++)
    #pragma unroll
    for (int i = 0; i < 4; i++) {
      m0r = fmaxf(m0r, sc[0][f][i]);
      m1r = fmaxf(m1r, sc[1][f][i]);
    }
  m0r = fmaxf(m0r, __shfl_xor(m0r, 16)); m0r = fmaxf(m0r, __shfl_xor(m0r, 32));
  m1r = fmaxf(m1r, __shfl_xor(m1r, 16)); m1r = fmaxf(m1r, __shfl_xor(m1r, 32));
  if (lk == 0) { redM[lr][w] = m0r; redM[16 + lr][w] = m1r; }
  __syncthreads();
  {
    float4 a = *(const float4*)&redM[lr][0];
    float4 bq = *(const float4*)&redM[lr][4];
    m0r = fmaxf(fmaxf(fmaxf(a.x, a.y), fmaxf(a.z, a.w)),
                fmaxf(fmaxf(bq.x, bq.y), fmaxf(bq.z, bq.w)));
    float4 c = *(const float4*)&redM[16 + lr][0];
    float4 d = *(const float4*)&redM[16 + lr][4];
    m1r = fmaxf(fmaxf(fmaxf(c.x, c.y), fmaxf(c.z, c.w)),
                fmaxf(fmaxf(d.x, d.y), fmaxf(d.z, d.w)));
  }
  float s0 = 0.f, s1 = 0.f;
  #pragma unroll
  for (int f = 0; f < 8; f++)
    #pragma unroll
    for (int i = 0; i < 4; i++) {
      sc[0][f][i] = __expf(sc[0][f][i] - m0r); s0 += sc[0][f][i];
      sc[1][f][i] = __expf(sc[1][f][i] - m1r); s1 += sc[1][f][i];
    }
  s0 += __shfl_xor(s0, 16); s0 += __shfl_xor(s0, 32);
  s1 += __shfl_xor(s1, 16); s1 += __shfl_xor(s1, 32);
  if (lk == 0) { redS[lr][w] = s0; redS[16 + lr][w] = s1; }
  __syncthreads();
  float inv0, inv1;
  {
    float4 a = *(const float4*)&redS[lr][0];
    float4 bq = *(const float4*)&redS[lr][4];
    inv0 = 1.0f / (a.x + a.y + a.z + a.w + bq.x + bq.y + bq.z + bq.w);
    float4 c = *(const float4*)&redS[16 + lr][0];
    float4 d = *(const float4*)&redS[16 + lr][4];
    inv1 = 1.0f / (c.x + c.y + c.z + c.w + d.x + d.y + d.z + d.w);
  }

  // ---- P (bf16) -> LDS, swizzled: row qb*16+lr, col w*128 + cc*16 + 4lk ----
  #pragma unroll
  for (int qb = 0; qb < 2; qb++) {
    float invq = qb ? inv1 : inv0;
    int row = qb * 16 + lr;
    #pragma unroll
    for (int cc = 0; cc < 8; cc++) {
      union { ushort u[4]; uint2 d; } pk;
      pk.u[0] = (ushort)f2bfbits(sc[qb][cc][0] * invq);
      pk.u[1] = (ushort)f2bfbits(sc[qb][cc][1] * invq);
      pk.u[2] = (ushort)f2bfbits(sc[qb][cc][2] * invq);
      pk.u[3] = (ushort)f2bfbits(sc[qb][cc][3] * invq);
      int slot_lin = w * 16 + cc * 2 + (lk >> 1);
      int addr = row * 2048 + ((slot_lin ^ (row & 7)) << 4) + ((lk & 1) << 3);
      *(uint2*)((char*)P + addr) = pk.d;
    }
  }
  __syncthreads();   // P visible to all waves

  // ---- stream attn out NOW (overlaps PV below): 4 rows/wave, 1KB lines ----
  #pragma unroll
  for (int rg = 0; rg < 4; rg++) {
    int row = w * 4 + rg;
    float* arow = attn + ((size_t)bh * 1024 + r0 + row) * 1024;
    int swr = row & 7;
    #pragma unroll
    for (int it = 0; it < 4; it++) {
      int ci = it * 64 + l;              // 16B output chunk (4 f32)
      uint2 d = *(const uint2*)((const char*)P + row * 2048 +
                                (((ci >> 1) ^ swr) << 4) + ((ci & 1) << 3));
      float4 o;
      o.x = __uint_as_float(d.x << 16);
      o.y = __uint_as_float(d.x & 0xffff0000u);
      o.z = __uint_as_float(d.y << 16);
      o.w = __uint_as_float(d.y & 0xffff0000u);
      *(float4*)&arow[ci * 4] = o;
    }
  }

  // ---- phase 3: ctx = P @ V; wave w: row-block rb=w>>2, dim-grp dg=w&3 ----
  const int dg = w & 3, rb = w >> 2;
  const int prow = rb * 16 + lr;
  const int psw = lr & 7;                 // (rb*16+lr)&7 == lr&7
  f32x4 o0 = {}, o1 = {};
  #pragma unroll
  for (int jj = 0; jj < 32; jj++) {
    const short* vfp = vf_ + (((size_t)(bh * 4 + dg) * 32 + jj) << 9);
    bfx8 bv = *(const bfx8*)&vfp[l * 8];
    int slot_lin = jj * 4 + lk;
    bfx8 pa = *(const bfx8*)((const char*)P + prow * 2048 +
                             ((slot_lin ^ psw) << 4));
    if (jj & 1) o1 = __builtin_amdgcn_mfma_f32_16x16x32_bf16(pa, bv, o1, 0, 0, 0);
    else        o0 = __builtin_amdgcn_mfma_f32_16x16x32_bf16(pa, bv, o0, 0, 0, 0);
  }
  #pragma unroll
  for (int i = 0; i < 4; i++) {
    float v = o0[i] + o1[i];
    ctx[(((size_t)b << 10) + r0 + rb * 16 + 4 * lk + i) * 1024 +
        (h << 6) + (dg << 4) + lr] = f2bfbits(v);
  }
}

// ---------------- launch ----------------

extern "C" void kernel_launch(void* const* d_in, const int* in_sizes, int n_in,
                              void* d_out, int out_size, void* d_ws, size_t ws_size,
                              hipStream_t stream) {
  const float* x    = (const float*)d_in[0];
  const int*   mask = (const int*)d_in[1];
  const float* Wqkv = (const float*)d_in[2];
  const float* bqkv = (const float*)d_in[3];
  const float* Wout = (const float*)d_in[4];
  const float* bout = (const float*)d_in[5];
  float* out  = (float*)d_out;
  float* attn = out + (size_t)4 * 1024 * 1024;

  char* ws = (char*)d_ws;
  short* xb    = (short*)(ws);                  //  8 MB  x bf16 [4096][1024]
  short* wqkvT = (short*)(ws + 8388608);        //  6 MB  [3072][1024]
  short* woutT = (short*)(ws + 14680064);       //  2 MB  [1024][1024]
  short* qfr   = (short*)(ws + 16777216);       //  8 MB  Q fragments
  short* kfr   = (short*)(ws + 25165824);       //  8 MB  K fragments
  short* vfr   = (short*)(ws + 33554432);       //  8 MB  V fragments
  short* ctx   = (short*)(ws + 41943040);       //  8 MB  [4096][1024]
  unsigned char* msk = (unsigned char*)(ws + 50331648);  // 4 KB

  k_prep<<<8208, 256, 0, stream>>>(x, xb, mask, msk, Wqkv, wqkvT, Wout, woutT);
  k_gemm<<<dim3(24, 32), 256, 0, stream>>>(xb, wqkvT, bqkv, 1024, qfr, kfr, vfr);
  k_attn<<<2048, 512, 0, stream>>>(qfr, kfr, vfr, msk, attn, ctx);
  k_gemm_out<<<dim3(16, 32), 256, 0, stream>>>(ctx, woutT, bout, out);
}